// Round 3
// baseline (726.315 us; speedup 1.0000x reference)
//
#include <hip/hip_runtime.h>

#define G 3
#define RR 2
#define NN 4096
#define DFEAT 64
#define DHID 64
#define DCLS 32
#define KS 4

typedef __attribute__((ext_vector_type(4))) float f32x4;
typedef __attribute__((ext_vector_type(8))) short short8;
typedef unsigned short u16;

__device__ __forceinline__ u16 f2bf(float f) {
  union { float f; unsigned u; } x; x.f = f;
  unsigned r = x.u + 0x7fffu + ((x.u >> 16) & 1u);   // RNE
  return (u16)(r >> 16);
}

// sT[gr][DOUT][NN] (bf16) = transpose(in[NN][DIN] @ W[gr][DIN][DOUT])
template<int DIN, int DOUT>
__global__ __launch_bounds__(256) void make_sT(const float* __restrict__ in,
                                               const float* __restrict__ W,
                                               u16* __restrict__ sT) {
  __shared__ float xsh[64][DIN + 1];
  __shared__ float wsh[DIN][DOUT + 1];
  const int gr = blockIdx.y;
  const int m0 = blockIdx.x * 64;
  const int t = threadIdx.x;
  for (int i = t; i < 64 * DIN; i += 256)
    xsh[i / DIN][i % DIN] = in[(size_t)(m0 + i / DIN) * DIN + (i % DIN)];
  for (int i = t; i < DIN * DOUT; i += 256)
    wsh[i / DOUT][i % DOUT] = W[(size_t)gr * DIN * DOUT + i];
  __syncthreads();
  constexpr int TPO = 256 / DOUT;   // threads per output column
  constexpr int MPT = 64 / TPO;     // m-rows per thread
  const int o = t / TPO;
  const int ms = (t % TPO) * MPT;
  for (int j = 0; j < MPT; ++j) {
    float acc = 0.f;
#pragma unroll
    for (int f = 0; f < DIN; ++f) acc += xsh[ms + j][f] * wsh[f][o];
    sT[((size_t)gr * DOUT + o) * NN + m0 + ms + j] = f2bf(acc);
  }
}

// hpart[ks][g][n][o] = sum_r adj[g][r][n][m-chunk] @ sT[g][r][o][m-chunk]^T
template<int DOUT>
__global__ __launch_bounds__(256) void gemm_adj(const float* __restrict__ adj,
                                                const u16* __restrict__ sT,
                                                float* __restrict__ hpart) {
  constexpr int NC = DOUT / 16;
  constexpr int MLEN = NN / KS;
  const int ks = blockIdx.x;
  const int ntile = blockIdx.y;
  const int g = blockIdx.z;
  const int wave = threadIdx.x >> 6;
  const int lane = threadIdx.x & 63;
  const int row16 = lane & 15;
  const int kg8 = (lane >> 4) * 8;      // 8 contiguous k per lane-group
  const int nbase = ntile * 64 + wave * 16;
  f32x4 acc[NC];
#pragma unroll
  for (int c = 0; c < NC; ++c) acc[c] = (f32x4){0.f, 0.f, 0.f, 0.f};
  const int m0 = ks * MLEN;
  for (int r = 0; r < RR; ++r) {
    const float* ab = adj + ((size_t)(g * RR + r) * NN + nbase + row16) * NN + kg8 + m0;
    const u16* bb = sT + (size_t)(g * RR + r) * DOUT * NN + kg8 + m0;
#pragma unroll 2
    for (int m = 0; m < MLEN; m += 32) {
      f32x4 a0 = *(const f32x4*)(ab + m);
      f32x4 a1 = *(const f32x4*)(ab + m + 4);
      union { short8 v; u16 u[8]; } af;
      af.u[0] = f2bf(a0[0]); af.u[1] = f2bf(a0[1]);
      af.u[2] = f2bf(a0[2]); af.u[3] = f2bf(a0[3]);
      af.u[4] = f2bf(a1[0]); af.u[5] = f2bf(a1[1]);
      af.u[6] = f2bf(a1[2]); af.u[7] = f2bf(a1[3]);
#pragma unroll
      for (int c = 0; c < NC; ++c) {
        short8 bf = *(const short8*)(bb + (size_t)(c * 16 + row16) * NN + m);
        acc[c] = __builtin_amdgcn_mfma_f32_16x16x32_bf16(af.v, bf, acc[c], 0, 0, 0);
      }
    }
  }
  // C/D layout (m89-verified): col = lane&15, row = (lane>>4)*4 + reg
  const int rsub = (lane >> 4) * 4;
#pragma unroll
  for (int c = 0; c < NC; ++c) {
    const int o = c * 16 + row16;
#pragma unroll
    for (int j = 0; j < 4; ++j) {
      const int n = nbase + rsub + j;
      hpart[(((size_t)ks * G + g) * NN + n) * DOUT + o] = acc[c][j];
    }
  }
}

// sq[g] += sum_{n,d} relu(sum_ks hpart + b)   (divide by N*DOUT later)
template<int DOUT>
__global__ __launch_bounds__(256) void reduce_sq(const float* __restrict__ hpart,
                                                 const float* __restrict__ b,
                                                 float* __restrict__ sq) {
  const int g = blockIdx.y;
  const size_t stride = (size_t)G * NN * DOUT;
  const float* hp = hpart + (size_t)g * NN * DOUT;
  float acc = 0.f;
  for (int i = blockIdx.x * 256 + threadIdx.x; i < NN * DOUT; i += gridDim.x * 256) {
    float v = b[g * DOUT + (i & (DOUT - 1))];
#pragma unroll
    for (int ks = 0; ks < KS; ++ks) v += hp[ks * stride + i];
    acc += fmaxf(v, 0.f);
  }
#pragma unroll
  for (int off = 32; off; off >>= 1) acc += __shfl_down(acc, off, 64);
  __shared__ float ls[4];
  if ((threadIdx.x & 63) == 0) ls[threadIdx.x >> 6] = acc;
  __syncthreads();
  if (threadIdx.x == 0) atomicAdd(&sq[g], ls[0] + ls[1] + ls[2] + ls[3]);
}

// out[n][d] = sum_g a[g] * relu(sum_ks hpart + b),  a = softmax(relu(sq@Wk)@Wq)
template<int DOUT>
__global__ __launch_bounds__(256) void combine(const float* __restrict__ hpart,
                                               const float* __restrict__ b,
                                               const float* __restrict__ sq,
                                               const float* __restrict__ Wk,
                                               const float* __restrict__ Wq,
                                               float* __restrict__ out) {
  float a0, a1, a2;
  {
    float sm[3], kk[3], lg[3];
#pragma unroll
    for (int g2 = 0; g2 < 3; ++g2) sm[g2] = sq[g2] * (1.0f / ((float)NN * DOUT));
#pragma unroll
    for (int j = 0; j < 3; ++j)
      kk[j] = fmaxf(sm[0] * Wk[j] + sm[1] * Wk[3 + j] + sm[2] * Wk[6 + j], 0.f);
#pragma unroll
    for (int j = 0; j < 3; ++j)
      lg[j] = kk[0] * Wq[j] + kk[1] * Wq[3 + j] + kk[2] * Wq[6 + j];
    float mx = fmaxf(lg[0], fmaxf(lg[1], lg[2]));
    float e0 = expf(lg[0] - mx), e1 = expf(lg[1] - mx), e2 = expf(lg[2] - mx);
    float s = e0 + e1 + e2;
    a0 = e0 / s; a1 = e1 / s; a2 = e2 / s;
  }
  const size_t gs = (size_t)NN * DOUT;
  const size_t ksstride = (size_t)G * gs;
  for (size_t i = (size_t)blockIdx.x * blockDim.x + threadIdx.x; i < gs;
       i += (size_t)gridDim.x * blockDim.x) {
    const int d = (int)(i & (DOUT - 1));
    float v = 0.f;
#pragma unroll
    for (int g2 = 0; g2 < 3; ++g2) {
      float h = b[g2 * DOUT + d];
#pragma unroll
      for (int ks = 0; ks < KS; ++ks) h += hpart[ks * ksstride + g2 * gs + i];
      const float ag = (g2 == 0) ? a0 : ((g2 == 1) ? a1 : a2);
      v += ag * fmaxf(h, 0.f);
    }
    out[i] = v;
  }
}

extern "C" void kernel_launch(void* const* d_in, const int* in_sizes, int n_in,
                              void* d_out, int out_size, void* d_ws, size_t ws_size,
                              hipStream_t stream) {
  const float* x   = (const float*)d_in[0];
  const float* adj = (const float*)d_in[1];
  const float* W1  = (const float*)d_in[2];
  const float* b1  = (const float*)d_in[3];
  const float* W2  = (const float*)d_in[4];
  const float* b2  = (const float*)d_in[5];
  const float* Wk  = (const float*)d_in[6];
  const float* Wq  = (const float*)d_in[7];
  float* out = (float*)d_out;

  char* ws = (char*)d_ws;
  size_t off = 0;
  float* hpart1 = (float*)(ws + off); off += (size_t)KS * G * NN * DHID * 4;   // 12.6 MB
  float* hpart2 = (float*)(ws + off); off += (size_t)KS * G * NN * DCLS * 4;   // 6.3 MB
  float* sq1 = (float*)(ws + off);
  float* sq2 = sq1 + 16;              off += 256;
  u16* s1T = (u16*)(ws + off);        off += (size_t)G * RR * DHID * NN * 2;   // 6.3 MB
  float* out1 = (float*)(ws + off);   off += (size_t)NN * DHID * 4;            // 1 MB
  u16* s2T = (u16*)(ws + off);        off += (size_t)G * RR * DCLS * NN * 2;   // 1.6 MB

  hipMemsetAsync(sq1, 0, 256, stream);

  // Layer 1
  make_sT<DFEAT, DHID><<<dim3(NN / 64, G * RR), 256, 0, stream>>>(x, W1, s1T);
  gemm_adj<DHID><<<dim3(KS, NN / 64, G), 256, 0, stream>>>(adj, s1T, hpart1);
  reduce_sq<DHID><<<dim3(32, G), 256, 0, stream>>>(hpart1, b1, sq1);
  combine<DHID><<<dim3(256), 256, 0, stream>>>(hpart1, b1, sq1, Wk, Wq, out1);
  // Layer 2
  make_sT<DHID, DCLS><<<dim3(NN / 64, G * RR), 256, 0, stream>>>(out1, W2, s2T);
  gemm_adj<DCLS><<<dim3(KS, NN / 64, G), 256, 0, stream>>>(adj, s2T, hpart2);
  reduce_sq<DCLS><<<dim3(32, G), 256, 0, stream>>>(hpart2, b2, sq2);
  combine<DCLS><<<dim3(256), 256, 0, stream>>>(hpart2, b2, sq2, Wk + 9, Wq + 9, out);
}